// Round 13
// baseline (363.996 us; speedup 1.0000x reference)
//
#include <hip/hip_runtime.h>
#include <hip/hip_fp16.h>
#include <math.h>

#define NA 10000
#define NE 100000
#define PI_F 3.14159265358979323846f

// Row layout of the "uncoupled" per-atom pack: c-blocks of 3^c rows, 32 k each.
// rowOff = {0,1,4,13}, total 40 rows.
// uncf stored fp16, packed 8-rows-per-uint4: u4[a*160 + jj*32 + k] holds rows
// 8jj..8jj+7 at channel k (half2 pairs in .x/.y/.z/.w).
// csbuf (R14: fp16) is SLOT-ordered: csh[i*40 + row] = uint2 of 4 half
// per-lp coefficients. Halves kB2's dominant cold stream (64->32 MB) and
// kPrep's scattered write.
// U concat offsets: U0@0 (1), U1@1 (12), U2@13 (81), U3@94 (432) => 526 floats.
//
// SESSION LEDGER (measured):
//   R4/R12 config: 355.7/355.2us total; kB2 120.5-125 (124 VGPR, no spill),
//   kC_out ~62, rest ~168.
//   kB2 FAILED restructures: cross-iter SWP (compiler copy-propagated the
//   rotation, 240us); in-wave coeff reconstruction (serial LDS chain + bank
//   conflicts, 170us); persistent atom queue (acc[40] spilled, 219us);
//   (256,4) bound (allocator targets 64 VGPR -> spill, 343us); 2-edge
//   intra-iter unroll (allocator caps at 128 VGPR -> spill, 307us).
//   kB2 is latency-bound; the R2 loop form is a local optimum: live set just
//   under 128 VGPR, 5 gathers in flight, no barriers. DO NOT mutate the loop.

__device__ __forceinline__ constexpr int rowC(int row) {
    return (row == 0) ? 0 : (row < 4) ? 1 : (row < 13) ? 2 : 3;
}

__device__ __forceinline__ void stage_U(const float* __restrict__ U0,
                                        const float* __restrict__ U1,
                                        const float* __restrict__ U2,
                                        const float* __restrict__ U3,
                                        float* uLds, int t, int nthr) {
    for (int i = t; i < 526; i += nthr) {
        float v;
        if (i == 0)       v = U0[0];
        else if (i < 13)  v = U1[i - 1];
        else if (i < 94)  v = U2[i - 13];
        else              v = U3[i - 94];
        uLds[i] = v;
    }
}

// ---------------- kCountScan: fused count (LDS atomics) + scan --------------
// R14: replaces memset + kCount + kScan (3 dispatches, global counts
// round-trip) with one single-block kernel. cnt in LDS (40 KB), 100k LDS
// atomicAdds over 1024 threads, then the verified scan logic unchanged.
__global__ __launch_bounds__(1024) void kCountScan(
    const int* __restrict__ centers,
    int* __restrict__ offsets, int* __restrict__ cursor)
{
    __shared__ int cnt[NA];
    __shared__ int sums[1024];
    const int t = threadIdx.x;
    for (int i = t; i < NA; i += 1024) cnt[i] = 0;
    __syncthreads();
    for (int e = t; e < NE; e += 1024) atomicAdd(&cnt[centers[e]], 1);
    __syncthreads();

    const int base = t * 10;
    int local[10];
    int s = 0;
#pragma unroll
    for (int j = 0; j < 10; ++j) {
        int idx = base + j;
        int v = (idx < NA) ? cnt[idx] : 0;
        local[j] = s;
        s += v;
    }
    sums[t] = s;
    __syncthreads();
    for (int off = 1; off < 1024; off <<= 1) {
        int v = (t >= off) ? sums[t - off] : 0;
        __syncthreads();
        sums[t] += v;
        __syncthreads();
    }
    const int prev = (t == 0) ? 0 : sums[t - 1];
#pragma unroll
    for (int j = 0; j < 10; ++j) {
        int idx = base + j;
        if (idx <= NA) {
            int o = prev + local[j];
            offsets[idx] = o;
            if (idx < NA) cursor[idx] = o;
        }
    }
}

// ---------------- kPrep: [0,1250) atoms ; [1250,1641) edges (scatter fused) ----
__global__ __launch_bounds__(256) void kPrep(
    const float* __restrict__ f0, const float* __restrict__ f1,
    const float* __restrict__ f2, const float* __restrict__ f3,
    const float* __restrict__ r,
    const float* __restrict__ sh0, const float* __restrict__ sh1,
    const float* __restrict__ sh2, const float* __restrict__ sh3,
    const float* __restrict__ U0, const float* __restrict__ U1,
    const float* __restrict__ U2, const float* __restrict__ U3,
    const int* __restrict__ centers, const int* __restrict__ neighbors,
    int* __restrict__ cursor,
    uint4* __restrict__ uncf16, float* __restrict__ rbbuf,
    uint2* __restrict__ csh, int* __restrict__ nbrs)
{
    __shared__ float uLds[526];
    const int t = threadIdx.x;
    stage_U(U0, U1, U2, U3, uLds, t, 256);
    __syncthreads();

    if (blockIdx.x < 1250) {
        // ---- atom part: 8 atoms/block, 32 k-lanes each ----
        const int la = t >> 5, k = t & 31;
        const int a = blockIdx.x * 8 + la;
        float arr[40];

        { // c = 0 (base 96)
            arr[0] = uLds[0] * f0[(size_t)a * 128 + 96 + k];
        }
        { // c = 1 (base 64)
            float x[4];
            x[0] = f0[(size_t)a * 128 + 64 + k];
#pragma unroll
            for (int m = 0; m < 3; ++m) x[1 + m] = f1[(size_t)a * 288 + m * 96 + 64 + k];
#pragma unroll
            for (int d = 0; d < 3; ++d) {
                float acc = 0.f;
#pragma unroll
                for (int m = 0; m < 4; ++m) acc += uLds[1 + d * 4 + m] * x[m];
                arr[1 + d] = acc;
            }
        }
        { // c = 2 (base 32)
            float x[9];
            x[0] = f0[(size_t)a * 128 + 32 + k];
#pragma unroll
            for (int m = 0; m < 3; ++m) x[1 + m] = f1[(size_t)a * 288 + m * 96 + 32 + k];
#pragma unroll
            for (int m = 0; m < 5; ++m) x[4 + m] = f2[(size_t)a * 320 + m * 64 + 32 + k];
#pragma unroll
            for (int d = 0; d < 9; ++d) {
                float acc = 0.f;
#pragma unroll
                for (int m = 0; m < 9; ++m) acc += uLds[13 + d * 9 + m] * x[m];
                arr[4 + d] = acc;
            }
        }
        { // c = 3 (base 0)
            float x[16];
            x[0] = f0[(size_t)a * 128 + k];
#pragma unroll
            for (int m = 0; m < 3; ++m) x[1 + m] = f1[(size_t)a * 288 + m * 96 + k];
#pragma unroll
            for (int m = 0; m < 5; ++m) x[4 + m] = f2[(size_t)a * 320 + m * 64 + k];
#pragma unroll
            for (int m = 0; m < 7; ++m) x[9 + m] = f3[(size_t)a * 224 + m * 32 + k];
#pragma unroll
            for (int d = 0; d < 27; ++d) {
                float acc = 0.f;
#pragma unroll
                for (int m = 0; m < 16; ++m) acc += uLds[94 + d * 16 + m] * x[m];
                arr[13 + d] = acc;
            }
        }
        uint4* op = uncf16 + (size_t)a * 160 + k;
#pragma unroll
        for (int jj = 0; jj < 5; ++jj) {
            uint4 w;
            __half2 h0 = __floats2half2_rn(arr[8 * jj + 0], arr[8 * jj + 1]);
            __half2 h1 = __floats2half2_rn(arr[8 * jj + 2], arr[8 * jj + 3]);
            __half2 h2 = __floats2half2_rn(arr[8 * jj + 4], arr[8 * jj + 5]);
            __half2 h3 = __floats2half2_rn(arr[8 * jj + 6], arr[8 * jj + 7]);
            w.x = *(unsigned int*)&h0; w.y = *(unsigned int*)&h1;
            w.z = *(unsigned int*)&h2; w.w = *(unsigned int*)&h3;
            op[jj * 32] = w;
        }
    } else {
        // ---- edge part: scatter to CSR slot + coefficients + radial basis ----
        const int e = (blockIdx.x - 1250) * 256 + t;
        if (e >= NE) return;

        const int c_ = centers[e];
        const int pos = atomicAdd(&cursor[c_], 1);
        nbrs[pos] = neighbors[e];

        float shv[16];
        shv[0] = sh0[e];
#pragma unroll
        for (int m = 0; m < 3; ++m) shv[1 + m] = sh1[(size_t)e * 3 + m];
#pragma unroll
        for (int m = 0; m < 5; ++m) shv[4 + m] = sh2[(size_t)e * 5 + m];
#pragma unroll
        for (int m = 0; m < 7; ++m) shv[9 + m] = sh3[(size_t)e * 7 + m];

        const float rv = r[e];
        const float fc = 0.5f * (cosf(PI_F * fminf(rv * 0.2f, 1.0f)) + 1.0f);
        const float pref = fc / (rv + 1e-6f);
        const float step = rv * (PI_F * 0.2f);
        float4 ra, rb;
        ra.x = sinf(1.f * step) * pref; ra.y = sinf(2.f * step) * pref;
        ra.z = sinf(3.f * step) * pref; ra.w = sinf(4.f * step) * pref;
        rb.x = sinf(5.f * step) * pref; rb.y = sinf(6.f * step) * pref;
        rb.z = sinf(7.f * step) * pref; rb.w = sinf(8.f * step) * pref;
        *(float4*)(rbbuf + (size_t)pos * 8)     = ra;
        *(float4*)(rbbuf + (size_t)pos * 8 + 4) = rb;

        const int UO[4] = {0, 1, 13, 94};
        const int RO[4] = {0, 1, 4, 13};
        const int P3[4] = {1, 3, 9, 27};
        uint2* cso = csh + (size_t)pos * 40;
#pragma unroll
        for (int c = 0; c < 4; ++c) {
            const int M2 = (c + 1) * (c + 1);
            for (int d = 0; d < P3[c]; ++d) {
                float cv[4] = {0.f, 0.f, 0.f, 0.f};
#pragma unroll
                for (int lp = 0; lp < 4; ++lp) {
                    if (lp > c) break;
                    float s = 0.f;
#pragma unroll
                    for (int ml = 0; ml < 2 * lp + 1; ++ml)
                        s += uLds[UO[c] + d * M2 + lp * lp + ml] * shv[lp * lp + ml];
                    cv[lp] = s;
                }
                __half2 h0 = __floats2half2_rn(cv[0], cv[1]);
                __half2 h1 = __floats2half2_rn(cv[2], cv[3]);
                uint2 u;
                u.x = *(unsigned int*)&h0;
                u.y = *(unsigned int*)&h1;
                cso[RO[c] + d] = u;
            }
        }
    }
}

// ---------------- kB2: wave-per-atom accumulation (R2 form, verified 120us) --
// Loop structure FROZEN (local optimum). R14 delta: cs rows read as fp16
// uint2 (8B) instead of float4 (16B) -> csbuf stream 64->32 MB; +4 cvt/row
// absorbed by latency slack. Tripwire: WRITE_SIZE > 60MB => spill => revert.
__global__ __launch_bounds__(256, 2) void kB2(
    const float* __restrict__ Wr0, const float* __restrict__ Wr1,
    const float* __restrict__ Wr2, const float* __restrict__ Wr3,
    const int* __restrict__ offsets, const int* __restrict__ nbrs,
    const float* __restrict__ rbbuf, const uint2* __restrict__ csh,
    const uint4* __restrict__ uncf16, float* __restrict__ pooled)
{
    __shared__ float wLds[2560];      // Wrad0..3 concat: 1024,768,512,256
    const int t = threadIdx.x;
    for (int i = t; i < 2560; i += 256) {
        float v;
        if (i < 1024)      v = Wr0[i];
        else if (i < 1792) v = Wr1[i - 1024];
        else if (i < 2304) v = Wr2[i - 1792];
        else               v = Wr3[i - 2304];
        wLds[i] = v;
    }
    __syncthreads();

    const int lane = t & 63;
    const int wv = t >> 6;            // wave id 0..3 -> atom
    const int k = lane & 31;
    const int g2 = lane >> 5;         // slot parity within wave
    const int a = blockIdx.x * 4 + wv;
    const int beg = offsets[a], end = offsets[a + 1];

    float acc[40];
#pragma unroll
    for (int i = 0; i < 40; ++i) acc[i] = 0.f;

    const int KL[4] = {128, 96, 64, 32};
    const int WO[4] = {0, 1024, 1792, 2304};

    int i = beg + g2;
    int nbr = (i < end) ? nbrs[i] : 0;
    for (; i < end; i += 2) {
        // prefetch next slot's neighbor index (breaks dependent chain)
        const int nbr_nx = (i + 2 < end) ? nbrs[i + 2] : 0;

        // issue all 5 gathers for this edge up front; rad compute covers them
        const uint4* up = uncf16 + (size_t)nbr * 160 + k;
        const uint4 w0 = up[0 * 32];
        const uint4 w1 = up[1 * 32];
        const uint4 w2 = up[2 * 32];
        const uint4 w3 = up[3 * 32];
        const uint4 w4 = up[4 * 32];

        const float4 r0 = *(const float4*)(rbbuf + (size_t)i * 8);
        const float4 r1 = *(const float4*)(rbbuf + (size_t)i * 8 + 4);
        const float rb[8] = {r0.x, r0.y, r0.z, r0.w, r1.x, r1.y, r1.z, r1.w};

        float rad[4][4];
#pragma unroll
        for (int lp = 0; lp < 4; ++lp) {
#pragma unroll
            for (int c = 0; c < 4; ++c) {
                if (c < lp) continue;
                const int base = 32 * (3 - c);
                float s = 0.f;
#pragma unroll
                for (int n = 0; n < 8; ++n)
                    s += rb[n] * wLds[WO[lp] + n * KL[lp] + base + k];
                rad[lp][c] = s;
            }
        }

        const uint2* cs = csh + (size_t)i * 40;
        const uint4 ww[5] = {w0, w1, w2, w3, w4};
#pragma unroll
        for (int jj = 0; jj < 5; ++jj) {
            const unsigned int ws[4] = {ww[jj].x, ww[jj].y, ww[jj].z, ww[jj].w};
#pragma unroll
            for (int p2 = 0; p2 < 4; ++p2) {
                const int row0 = 8 * jj + 2 * p2, row1 = row0 + 1;
                const int c0 = rowC(row0), c1 = rowC(row1);
                const __half2 h = *(const __half2*)&ws[p2];
                const uint2 ua = cs[row0];
                const uint2 ub = cs[row1];
                const __half2 a01 = *(const __half2*)&ua.x;
                const __half2 a23 = *(const __half2*)&ua.y;
                const __half2 b01 = *(const __half2*)&ub.x;
                const __half2 b23 = *(const __half2*)&ub.y;
                float uv0 = __low2float(a01) * rad[0][c0];
                if (c0 >= 1) uv0 += __high2float(a01) * rad[1][c0];
                if (c0 >= 2) uv0 += __low2float(a23) * rad[2][c0];
                if (c0 >= 3) uv0 += __high2float(a23) * rad[3][c0];
                float uv1 = __low2float(b01) * rad[0][c1];
                if (c1 >= 1) uv1 += __high2float(b01) * rad[1][c1];
                if (c1 >= 2) uv1 += __low2float(b23) * rad[2][c1];
                if (c1 >= 3) uv1 += __high2float(b23) * rad[3][c1];
                acc[row0] += uv0 * __low2float(h);
                acc[row1] += uv1 * __high2float(h);
            }
        }
        nbr = nbr_nx;
    }

    // fold slot parities within the wave; both halves end with the total
#pragma unroll
    for (int row = 0; row < 40; ++row) acc[row] += __shfl_xor(acc[row], 32);

    // lower half writes rows 0..19, upper half rows 20..39 (coalesced per row)
    float* pp = pooled + (size_t)a * 1280 + k;
#pragma unroll
    for (int rr = 0; rr < 20; ++rr) {
        const float v   = g2 ? acc[rr + 20] : acc[rr];
        const int  row  = g2 ? (rr + 20)    : rr;
        pp[row * 32] = v;
    }
}

// ---------------- Kernel C: couple back + linear + residual ----------------
// R8: (a) float4 staging of pooled; (b) clds padded to stride 33 (kills the
// 6.72M-cycle bank conflicts measured at stride 32); (c) c-segmented couple
// phase with wave-aligned boundaries. Measured ~62 us (derived).
__global__ __launch_bounds__(256) void kC_out(
    const float* __restrict__ pooled,
    const float* __restrict__ f0, const float* __restrict__ f1,
    const float* __restrict__ f2, const float* __restrict__ f3,
    const float* __restrict__ U0, const float* __restrict__ U1,
    const float* __restrict__ U2, const float* __restrict__ U3,
    const float* __restrict__ W0, const float* __restrict__ W1,
    const float* __restrict__ W2, const float* __restrict__ W3,
    float* __restrict__ out)
{
    __shared__ float uLds[526];
    __shared__ float plds[4 * 1280];
    __shared__ float clds[120 * 33];  // row = la*30 + crowBase[c] + (m-index), padded stride 33
    const int t = threadIdx.x;
    stage_U(U0, U1, U2, U3, uLds, t, 256);
    const int a0 = blockIdx.x * 4;
    {
        const float4* src = (const float4*)(pooled + (size_t)a0 * 1280);
        float4* dst = (float4*)plds;
        for (int i = t; i < 1280; i += 256) dst[i] = src[i];
    }
    __syncthreads();

    // ---- couple back: clds = U^T . plds, c-segmented ----
    // c = 0: 128 units (la,1 row,32 kk); nd = 1
    if (t < 128) {
        const int la = t >> 5, kk = t & 31;
        clds[(la * 30 + 0) * 33 + kk] = uLds[0] * plds[la * 1280 + 0 * 32 + kk];
    }
    // c = 1: 512 units; M2 = 4, nd = 3, UO = 1, RO = 1, crowBase = 1
#pragma unroll
    for (int s = t; s < 512; s += 256) {
        const int la = s >> 7, rem = s & 127;
        const int m = rem >> 5, kk = rem & 31;
        float acc = 0.f;
#pragma unroll
        for (int d = 0; d < 3; ++d)
            acc += uLds[1 + d * 4 + m] * plds[la * 1280 + (1 + d) * 32 + kk];
        clds[(la * 30 + 1 + m) * 33 + kk] = acc;
    }
    // c = 2: 1152 units; M2 = 9, nd = 9, UO = 13, RO = 4, crowBase = 5
    for (int s = t; s < 1152; s += 256) {
        const int la = s / 288, rem = s - la * 288;
        const int m = rem >> 5, kk = rem & 31;
        float acc = 0.f;
#pragma unroll
        for (int d = 0; d < 9; ++d)
            acc += uLds[13 + d * 9 + m] * plds[la * 1280 + (4 + d) * 32 + kk];
        clds[(la * 30 + 5 + m) * 33 + kk] = acc;
    }
    // c = 3: 2048 units; M2 = 16, nd = 27, UO = 94, RO = 13, crowBase = 14
    for (int s = t; s < 2048; s += 256) {
        const int la = s >> 9, rem = s & 511;
        const int m = rem >> 5, kk = rem & 31;
        float acc = 0.f;
#pragma unroll
        for (int d = 0; d < 27; ++d)
            acc += uLds[94 + d * 16 + m] * plds[la * 1280 + (13 + d) * 32 + kk];
        clds[(la * 30 + 14 + m) * 33 + kk] = acc;
    }
    __syncthreads();

    // ---- linear + residual: static thread -> (l, m, q) map; 240 active ----
    int l, m, q;
    bool active = true;
    if (t < 32)       { l = 0; m = 0;                               q = 4 * t; }
    else if (t < 104) { l = 1; int u = t - 32;  m = u / 24; q = 4 * (u % 24); }
    else if (t < 184) { l = 2; int u = t - 104; m = u / 16; q = 4 * (u % 16); }
    else if (t < 240) { l = 3; int u = t - 184; m = u / 8;  q = 4 * (u % 8);  }
    else active = false;

    if (active) {
        const int K  = (l == 0) ? 128 : (l == 1) ? 96 : (l == 2) ? 64 : 32;
        const int MK = (l == 0) ? 128 : (l == 1) ? 288 : (l == 2) ? 320 : 224;
        const size_t Ol = (l == 0) ? 0 : (l == 1) ? 1280000 : (l == 2) ? 4160000 : 7360000;
        const float* F = (l == 0) ? f0 : (l == 1) ? f1 : (l == 2) ? f2 : f3;
        const float* W = (l == 0) ? W0 : (l == 1) ? W1 : (l == 2) ? W2 : W3;
        const int CRB[4] = {0, 1, 5, 14};   // crowBase per c-block

        float4 acc[4];
#pragma unroll
        for (int la = 0; la < 4; ++la)
            acc[la] = *(const float4*)(F + (size_t)(a0 + la) * MK + m * K + q);

        for (int j = 0; j < 4 - l; ++j) {
            const int c = l + j;
            const int crow = CRB[c] + l * l + m;   // row within atom's 30 coupled rows
#pragma unroll
            for (int kk = 0; kk < 32; ++kk) {
                const float4 w = *(const float4*)(W + (size_t)(32 * j + kk) * K + q);
#pragma unroll
                for (int la = 0; la < 4; ++la) {
                    const float cv = clds[(la * 30 + crow) * 33 + kk];
                    acc[la].x += cv * w.x; acc[la].y += cv * w.y;
                    acc[la].z += cv * w.z; acc[la].w += cv * w.w;
                }
            }
        }
#pragma unroll
        for (int la = 0; la < 4; ++la)
            *(float4*)(out + Ol + (size_t)(a0 + la) * MK + m * K + q) = acc[la];
    }
}

extern "C" void kernel_launch(void* const* d_in, const int* in_sizes, int n_in,
                              void* d_out, int out_size, void* d_ws, size_t ws_size,
                              hipStream_t stream)
{
    int ir, ish[4], ift[4], iwr[4], iu[4], iwl[4], ic, in_;
    if (in_sizes[2] == 300000) {
        ir = 0;
        for (int l = 0; l < 4; ++l) { ish[l] = 1 + l; ift[l] = 5 + l; iwr[l] = 9 + l; iu[l] = 13 + l; iwl[l] = 17 + l; }
        ic = 21; in_ = 22;
    } else {
        ir = 0;
        for (int l = 0; l < 4; ++l) { ish[l] = 1 + 5 * l; ift[l] = 2 + 5 * l; iwr[l] = 3 + 5 * l; iu[l] = 4 + 5 * l; iwl[l] = 5 + 5 * l; }
        ic = 21; in_ = 22;
    }
    const float* r   = (const float*)d_in[ir];
    const float* sh0 = (const float*)d_in[ish[0]];
    const float* sh1 = (const float*)d_in[ish[1]];
    const float* sh2 = (const float*)d_in[ish[2]];
    const float* sh3 = (const float*)d_in[ish[3]];
    const float* f0  = (const float*)d_in[ift[0]];
    const float* f1  = (const float*)d_in[ift[1]];
    const float* f2  = (const float*)d_in[ift[2]];
    const float* f3  = (const float*)d_in[ift[3]];
    const float* Wr0 = (const float*)d_in[iwr[0]];
    const float* Wr1 = (const float*)d_in[iwr[1]];
    const float* Wr2 = (const float*)d_in[iwr[2]];
    const float* Wr3 = (const float*)d_in[iwr[3]];
    const float* U0  = (const float*)d_in[iu[0]];
    const float* U1  = (const float*)d_in[iu[1]];
    const float* U2  = (const float*)d_in[iu[2]];
    const float* U3  = (const float*)d_in[iu[3]];
    const float* Wl0 = (const float*)d_in[iwl[0]];
    const float* Wl1 = (const float*)d_in[iwl[1]];
    const float* Wl2 = (const float*)d_in[iwl[2]];
    const float* Wl3 = (const float*)d_in[iwl[3]];
    const int* centers   = (const int*)d_in[ic];
    const int* neighbors = (const int*)d_in[in_];

    uint4* uncf16 = (uint4*)d_ws;                            // NA*160 uint4 = 25.6 MB
    float* pooled = (float*)(uncf16 + (size_t)NA * 160);     // NA*1280 f32 = 51.2 MB
    float* rbbuf  = pooled + (size_t)NA * 1280;              // NE*8 f32    = 3.2 MB
    uint2* csh    = (uint2*)(rbbuf + (size_t)NE * 8);        // NE*40 uint2 = 32 MB
    int*   nbrs    = (int*)(csh + (size_t)NE * 40);          // NE
    int*   offsets = nbrs + NE;                              // NA+1
    int*   cursor  = offsets + NA + 1;                       // NA
    float* outp   = (float*)d_out;

    kCountScan<<<1, 1024, 0, stream>>>(centers, offsets, cursor);
    kPrep<<<1250 + (NE + 255) / 256, 256, 0, stream>>>(
        f0, f1, f2, f3, r, sh0, sh1, sh2, sh3, U0, U1, U2, U3,
        centers, neighbors, cursor, uncf16, rbbuf, csh, nbrs);
    kB2<<<NA / 4, 256, 0, stream>>>(Wr0, Wr1, Wr2, Wr3, offsets, nbrs,
                                    rbbuf, csh, uncf16, pooled);
    kC_out<<<NA / 4, 256, 0, stream>>>(pooled, f0, f1, f2, f3, U0, U1, U2, U3,
                                       Wl0, Wl1, Wl2, Wl3, outp);
}

// Round 14
// 346.843 us; speedup vs baseline: 1.0495x; 1.0495x over previous
//
#include <hip/hip_runtime.h>
#include <hip/hip_fp16.h>
#include <math.h>

#define NA 10000
#define NE 100000
#define PI_F 3.14159265358979323846f

// Row layout of the "uncoupled" per-atom pack: c-blocks of 3^c rows, 32 k each.
// rowOff = {0,1,4,13}, total 40 rows.
// uncf stored fp16, packed 8-rows-per-uint4: u4[a*160 + jj*32 + k] holds rows
// 8jj..8jj+7 at channel k (half2 pairs in .x/.y/.z/.w).
// csh (fp16) is SLOT-ordered: csh[i*40 + row] = uint2 of 4 half per-lp
// coefficients (R13: halved kB2's cs stream; kB2 124.6 -> 117.3us measured).
// U concat offsets: U0@0 (1), U1@1 (12), U2@13 (81), U3@94 (432) => 526 floats.
//
// SESSION LEDGER (measured):
//   R12 config: 355.2us (kB2 124.6 @124 VGPR, kC_out ~62, rest ~168).
//   R13: fp16 csh kB2 117.3 (helped, minor spill: VGPR 128, WRITE 65MB);
//        single-block kCountScan rest 168->185 (hurt, REVERTED here).
//   kB2 FAILED restructures: cross-iter SWP (compiler copy-propagated the
//   rotation, 240us); in-wave coeff reconstruction (serial LDS chain + bank
//   conflicts, 170us); persistent atom queue (acc[40] spilled, 219us);
//   (256,4) bound (allocator targets 64 VGPR -> spill, 343us); 2-edge
//   intra-iter unroll (allocator caps at 128 VGPR -> spill, 307us).
//   kB2 is latency-bound; the R2 loop form is a local optimum. DO NOT mutate
//   the loop structure.

__device__ __forceinline__ constexpr int rowC(int row) {
    return (row == 0) ? 0 : (row < 4) ? 1 : (row < 13) ? 2 : 3;
}

__device__ __forceinline__ void stage_U(const float* __restrict__ U0,
                                        const float* __restrict__ U1,
                                        const float* __restrict__ U2,
                                        const float* __restrict__ U3,
                                        float* uLds, int t, int nthr) {
    for (int i = t; i < 526; i += nthr) {
        float v;
        if (i == 0)       v = U0[0];
        else if (i < 13)  v = U1[i - 1];
        else if (i < 94)  v = U2[i - 13];
        else              v = U3[i - 94];
        uLds[i] = v;
    }
}

// ---------------- kCount ----------------
__global__ __launch_bounds__(256) void kCount(const int* __restrict__ centers,
                                              int* __restrict__ counts)
{
    const int e = blockIdx.x * 256 + threadIdx.x;
    if (e < NE) atomicAdd(&counts[centers[e]], 1);
}

// ---------------- kScan ----------------
__global__ __launch_bounds__(1024) void kScan(const int* __restrict__ counts,
                                              int* __restrict__ offsets,
                                              int* __restrict__ cursor)
{
    __shared__ int sums[1024];
    const int t = threadIdx.x;
    const int base = t * 10;
    int local[10];
    int s = 0;
#pragma unroll
    for (int j = 0; j < 10; ++j) {
        int idx = base + j;
        int v = (idx < NA) ? counts[idx] : 0;
        local[j] = s;
        s += v;
    }
    sums[t] = s;
    __syncthreads();
    for (int off = 1; off < 1024; off <<= 1) {
        int v = (t >= off) ? sums[t - off] : 0;
        __syncthreads();
        sums[t] += v;
        __syncthreads();
    }
    const int prev = (t == 0) ? 0 : sums[t - 1];
#pragma unroll
    for (int j = 0; j < 10; ++j) {
        int idx = base + j;
        if (idx <= NA) {
            int o = prev + local[j];
            offsets[idx] = o;
            if (idx < NA) cursor[idx] = o;
        }
    }
}

// ---------------- kPrep: [0,1250) atoms ; [1250,1641) edges (scatter fused) ----
__global__ __launch_bounds__(256) void kPrep(
    const float* __restrict__ f0, const float* __restrict__ f1,
    const float* __restrict__ f2, const float* __restrict__ f3,
    const float* __restrict__ r,
    const float* __restrict__ sh0, const float* __restrict__ sh1,
    const float* __restrict__ sh2, const float* __restrict__ sh3,
    const float* __restrict__ U0, const float* __restrict__ U1,
    const float* __restrict__ U2, const float* __restrict__ U3,
    const int* __restrict__ centers, const int* __restrict__ neighbors,
    int* __restrict__ cursor,
    uint4* __restrict__ uncf16, float* __restrict__ rbbuf,
    uint2* __restrict__ csh, int* __restrict__ nbrs)
{
    __shared__ float uLds[526];
    const int t = threadIdx.x;
    stage_U(U0, U1, U2, U3, uLds, t, 256);
    __syncthreads();

    if (blockIdx.x < 1250) {
        // ---- atom part: 8 atoms/block, 32 k-lanes each ----
        const int la = t >> 5, k = t & 31;
        const int a = blockIdx.x * 8 + la;
        float arr[40];

        { // c = 0 (base 96)
            arr[0] = uLds[0] * f0[(size_t)a * 128 + 96 + k];
        }
        { // c = 1 (base 64)
            float x[4];
            x[0] = f0[(size_t)a * 128 + 64 + k];
#pragma unroll
            for (int m = 0; m < 3; ++m) x[1 + m] = f1[(size_t)a * 288 + m * 96 + 64 + k];
#pragma unroll
            for (int d = 0; d < 3; ++d) {
                float acc = 0.f;
#pragma unroll
                for (int m = 0; m < 4; ++m) acc += uLds[1 + d * 4 + m] * x[m];
                arr[1 + d] = acc;
            }
        }
        { // c = 2 (base 32)
            float x[9];
            x[0] = f0[(size_t)a * 128 + 32 + k];
#pragma unroll
            for (int m = 0; m < 3; ++m) x[1 + m] = f1[(size_t)a * 288 + m * 96 + 32 + k];
#pragma unroll
            for (int m = 0; m < 5; ++m) x[4 + m] = f2[(size_t)a * 320 + m * 64 + 32 + k];
#pragma unroll
            for (int d = 0; d < 9; ++d) {
                float acc = 0.f;
#pragma unroll
                for (int m = 0; m < 9; ++m) acc += uLds[13 + d * 9 + m] * x[m];
                arr[4 + d] = acc;
            }
        }
        { // c = 3 (base 0)
            float x[16];
            x[0] = f0[(size_t)a * 128 + k];
#pragma unroll
            for (int m = 0; m < 3; ++m) x[1 + m] = f1[(size_t)a * 288 + m * 96 + k];
#pragma unroll
            for (int m = 0; m < 5; ++m) x[4 + m] = f2[(size_t)a * 320 + m * 64 + k];
#pragma unroll
            for (int m = 0; m < 7; ++m) x[9 + m] = f3[(size_t)a * 224 + m * 32 + k];
#pragma unroll
            for (int d = 0; d < 27; ++d) {
                float acc = 0.f;
#pragma unroll
                for (int m = 0; m < 16; ++m) acc += uLds[94 + d * 16 + m] * x[m];
                arr[13 + d] = acc;
            }
        }
        uint4* op = uncf16 + (size_t)a * 160 + k;
#pragma unroll
        for (int jj = 0; jj < 5; ++jj) {
            uint4 w;
            __half2 h0 = __floats2half2_rn(arr[8 * jj + 0], arr[8 * jj + 1]);
            __half2 h1 = __floats2half2_rn(arr[8 * jj + 2], arr[8 * jj + 3]);
            __half2 h2 = __floats2half2_rn(arr[8 * jj + 4], arr[8 * jj + 5]);
            __half2 h3 = __floats2half2_rn(arr[8 * jj + 6], arr[8 * jj + 7]);
            w.x = *(unsigned int*)&h0; w.y = *(unsigned int*)&h1;
            w.z = *(unsigned int*)&h2; w.w = *(unsigned int*)&h3;
            op[jj * 32] = w;
        }
    } else {
        // ---- edge part: scatter to CSR slot + coefficients + radial basis ----
        const int e = (blockIdx.x - 1250) * 256 + t;
        if (e >= NE) return;

        const int c_ = centers[e];
        const int pos = atomicAdd(&cursor[c_], 1);
        nbrs[pos] = neighbors[e];

        float shv[16];
        shv[0] = sh0[e];
#pragma unroll
        for (int m = 0; m < 3; ++m) shv[1 + m] = sh1[(size_t)e * 3 + m];
#pragma unroll
        for (int m = 0; m < 5; ++m) shv[4 + m] = sh2[(size_t)e * 5 + m];
#pragma unroll
        for (int m = 0; m < 7; ++m) shv[9 + m] = sh3[(size_t)e * 7 + m];

        const float rv = r[e];
        const float fc = 0.5f * (cosf(PI_F * fminf(rv * 0.2f, 1.0f)) + 1.0f);
        const float pref = fc / (rv + 1e-6f);
        const float step = rv * (PI_F * 0.2f);
        float4 ra, rb;
        ra.x = sinf(1.f * step) * pref; ra.y = sinf(2.f * step) * pref;
        ra.z = sinf(3.f * step) * pref; ra.w = sinf(4.f * step) * pref;
        rb.x = sinf(5.f * step) * pref; rb.y = sinf(6.f * step) * pref;
        rb.z = sinf(7.f * step) * pref; rb.w = sinf(8.f * step) * pref;
        *(float4*)(rbbuf + (size_t)pos * 8)     = ra;
        *(float4*)(rbbuf + (size_t)pos * 8 + 4) = rb;

        const int UO[4] = {0, 1, 13, 94};
        const int RO[4] = {0, 1, 4, 13};
        const int P3[4] = {1, 3, 9, 27};
        uint2* cso = csh + (size_t)pos * 40;
#pragma unroll
        for (int c = 0; c < 4; ++c) {
            const int M2 = (c + 1) * (c + 1);
            for (int d = 0; d < P3[c]; ++d) {
                float cv[4] = {0.f, 0.f, 0.f, 0.f};
#pragma unroll
                for (int lp = 0; lp < 4; ++lp) {
                    if (lp > c) break;
                    float s = 0.f;
#pragma unroll
                    for (int ml = 0; ml < 2 * lp + 1; ++ml)
                        s += uLds[UO[c] + d * M2 + lp * lp + ml] * shv[lp * lp + ml];
                    cv[lp] = s;
                }
                __half2 h0 = __floats2half2_rn(cv[0], cv[1]);
                __half2 h1 = __floats2half2_rn(cv[2], cv[3]);
                uint2 u;
                u.x = *(unsigned int*)&h0;
                u.y = *(unsigned int*)&h1;
                cso[RO[c] + d] = u;
            }
        }
    }
}

// ---------------- kB2: wave-per-atom accumulation (R2 form + fp16 cs) --------
// Loop structure FROZEN (local optimum). fp16 cs read (uint2, 8B/row):
// measured 117.3us vs 124.6 float4 (R13). Minor spill at VGPR 128 ceiling
// (WRITE 65MB vs 50 demand) - accepted, net win.
__global__ __launch_bounds__(256, 2) void kB2(
    const float* __restrict__ Wr0, const float* __restrict__ Wr1,
    const float* __restrict__ Wr2, const float* __restrict__ Wr3,
    const int* __restrict__ offsets, const int* __restrict__ nbrs,
    const float* __restrict__ rbbuf, const uint2* __restrict__ csh,
    const uint4* __restrict__ uncf16, float* __restrict__ pooled)
{
    __shared__ float wLds[2560];      // Wrad0..3 concat: 1024,768,512,256
    const int t = threadIdx.x;
    for (int i = t; i < 2560; i += 256) {
        float v;
        if (i < 1024)      v = Wr0[i];
        else if (i < 1792) v = Wr1[i - 1024];
        else if (i < 2304) v = Wr2[i - 1792];
        else               v = Wr3[i - 2304];
        wLds[i] = v;
    }
    __syncthreads();

    const int lane = t & 63;
    const int wv = t >> 6;            // wave id 0..3 -> atom
    const int k = lane & 31;
    const int g2 = lane >> 5;         // slot parity within wave
    const int a = blockIdx.x * 4 + wv;
    const int beg = offsets[a], end = offsets[a + 1];

    float acc[40];
#pragma unroll
    for (int i = 0; i < 40; ++i) acc[i] = 0.f;

    const int KL[4] = {128, 96, 64, 32};
    const int WO[4] = {0, 1024, 1792, 2304};

    int i = beg + g2;
    int nbr = (i < end) ? nbrs[i] : 0;
    for (; i < end; i += 2) {
        // prefetch next slot's neighbor index (breaks dependent chain)
        const int nbr_nx = (i + 2 < end) ? nbrs[i + 2] : 0;

        // issue all 5 gathers for this edge up front; rad compute covers them
        const uint4* up = uncf16 + (size_t)nbr * 160 + k;
        const uint4 w0 = up[0 * 32];
        const uint4 w1 = up[1 * 32];
        const uint4 w2 = up[2 * 32];
        const uint4 w3 = up[3 * 32];
        const uint4 w4 = up[4 * 32];

        const float4 r0 = *(const float4*)(rbbuf + (size_t)i * 8);
        const float4 r1 = *(const float4*)(rbbuf + (size_t)i * 8 + 4);
        const float rb[8] = {r0.x, r0.y, r0.z, r0.w, r1.x, r1.y, r1.z, r1.w};

        float rad[4][4];
#pragma unroll
        for (int lp = 0; lp < 4; ++lp) {
#pragma unroll
            for (int c = 0; c < 4; ++c) {
                if (c < lp) continue;
                const int base = 32 * (3 - c);
                float s = 0.f;
#pragma unroll
                for (int n = 0; n < 8; ++n)
                    s += rb[n] * wLds[WO[lp] + n * KL[lp] + base + k];
                rad[lp][c] = s;
            }
        }

        const uint2* cs = csh + (size_t)i * 40;
        const uint4 ww[5] = {w0, w1, w2, w3, w4};
#pragma unroll
        for (int jj = 0; jj < 5; ++jj) {
            const unsigned int ws[4] = {ww[jj].x, ww[jj].y, ww[jj].z, ww[jj].w};
#pragma unroll
            for (int p2 = 0; p2 < 4; ++p2) {
                const int row0 = 8 * jj + 2 * p2, row1 = row0 + 1;
                const int c0 = rowC(row0), c1 = rowC(row1);
                const __half2 h = *(const __half2*)&ws[p2];
                const uint2 ua = cs[row0];
                const uint2 ub = cs[row1];
                const __half2 a01 = *(const __half2*)&ua.x;
                const __half2 a23 = *(const __half2*)&ua.y;
                const __half2 b01 = *(const __half2*)&ub.x;
                const __half2 b23 = *(const __half2*)&ub.y;
                float uv0 = __low2float(a01) * rad[0][c0];
                if (c0 >= 1) uv0 += __high2float(a01) * rad[1][c0];
                if (c0 >= 2) uv0 += __low2float(a23) * rad[2][c0];
                if (c0 >= 3) uv0 += __high2float(a23) * rad[3][c0];
                float uv1 = __low2float(b01) * rad[0][c1];
                if (c1 >= 1) uv1 += __high2float(b01) * rad[1][c1];
                if (c1 >= 2) uv1 += __low2float(b23) * rad[2][c1];
                if (c1 >= 3) uv1 += __high2float(b23) * rad[3][c1];
                acc[row0] += uv0 * __low2float(h);
                acc[row1] += uv1 * __high2float(h);
            }
        }
        nbr = nbr_nx;
    }

    // fold slot parities within the wave; both halves end with the total
#pragma unroll
    for (int row = 0; row < 40; ++row) acc[row] += __shfl_xor(acc[row], 32);

    // lower half writes rows 0..19, upper half rows 20..39 (coalesced per row)
    float* pp = pooled + (size_t)a * 1280 + k;
#pragma unroll
    for (int rr = 0; rr < 20; ++rr) {
        const float v   = g2 ? acc[rr + 20] : acc[rr];
        const int  row  = g2 ? (rr + 20)    : rr;
        pp[row * 32] = v;
    }
}

// ---------------- Kernel C: couple back + linear + residual ----------------
// R8: (a) float4 staging of pooled; (b) clds padded to stride 33 (kills the
// 6.72M-cycle bank conflicts measured at stride 32); (c) c-segmented couple
// phase with wave-aligned boundaries. Measured ~62 us (derived).
__global__ __launch_bounds__(256) void kC_out(
    const float* __restrict__ pooled,
    const float* __restrict__ f0, const float* __restrict__ f1,
    const float* __restrict__ f2, const float* __restrict__ f3,
    const float* __restrict__ U0, const float* __restrict__ U1,
    const float* __restrict__ U2, const float* __restrict__ U3,
    const float* __restrict__ W0, const float* __restrict__ W1,
    const float* __restrict__ W2, const float* __restrict__ W3,
    float* __restrict__ out)
{
    __shared__ float uLds[526];
    __shared__ float plds[4 * 1280];
    __shared__ float clds[120 * 33];  // row = la*30 + crowBase[c] + (m-index), padded stride 33
    const int t = threadIdx.x;
    stage_U(U0, U1, U2, U3, uLds, t, 256);
    const int a0 = blockIdx.x * 4;
    {
        const float4* src = (const float4*)(pooled + (size_t)a0 * 1280);
        float4* dst = (float4*)plds;
        for (int i = t; i < 1280; i += 256) dst[i] = src[i];
    }
    __syncthreads();

    // ---- couple back: clds = U^T . plds, c-segmented ----
    // c = 0: 128 units (la,1 row,32 kk); nd = 1
    if (t < 128) {
        const int la = t >> 5, kk = t & 31;
        clds[(la * 30 + 0) * 33 + kk] = uLds[0] * plds[la * 1280 + 0 * 32 + kk];
    }
    // c = 1: 512 units; M2 = 4, nd = 3, UO = 1, RO = 1, crowBase = 1
#pragma unroll
    for (int s = t; s < 512; s += 256) {
        const int la = s >> 7, rem = s & 127;
        const int m = rem >> 5, kk = rem & 31;
        float acc = 0.f;
#pragma unroll
        for (int d = 0; d < 3; ++d)
            acc += uLds[1 + d * 4 + m] * plds[la * 1280 + (1 + d) * 32 + kk];
        clds[(la * 30 + 1 + m) * 33 + kk] = acc;
    }
    // c = 2: 1152 units; M2 = 9, nd = 9, UO = 13, RO = 4, crowBase = 5
    for (int s = t; s < 1152; s += 256) {
        const int la = s / 288, rem = s - la * 288;
        const int m = rem >> 5, kk = rem & 31;
        float acc = 0.f;
#pragma unroll
        for (int d = 0; d < 9; ++d)
            acc += uLds[13 + d * 9 + m] * plds[la * 1280 + (4 + d) * 32 + kk];
        clds[(la * 30 + 5 + m) * 33 + kk] = acc;
    }
    // c = 3: 2048 units; M2 = 16, nd = 27, UO = 94, RO = 13, crowBase = 14
    for (int s = t; s < 2048; s += 256) {
        const int la = s >> 9, rem = s & 511;
        const int m = rem >> 5, kk = rem & 31;
        float acc = 0.f;
#pragma unroll
        for (int d = 0; d < 27; ++d)
            acc += uLds[94 + d * 16 + m] * plds[la * 1280 + (13 + d) * 32 + kk];
        clds[(la * 30 + 14 + m) * 33 + kk] = acc;
    }
    __syncthreads();

    // ---- linear + residual: static thread -> (l, m, q) map; 240 active ----
    int l, m, q;
    bool active = true;
    if (t < 32)       { l = 0; m = 0;                               q = 4 * t; }
    else if (t < 104) { l = 1; int u = t - 32;  m = u / 24; q = 4 * (u % 24); }
    else if (t < 184) { l = 2; int u = t - 104; m = u / 16; q = 4 * (u % 16); }
    else if (t < 240) { l = 3; int u = t - 184; m = u / 8;  q = 4 * (u % 8);  }
    else active = false;

    if (active) {
        const int K  = (l == 0) ? 128 : (l == 1) ? 96 : (l == 2) ? 64 : 32;
        const int MK = (l == 0) ? 128 : (l == 1) ? 288 : (l == 2) ? 320 : 224;
        const size_t Ol = (l == 0) ? 0 : (l == 1) ? 1280000 : (l == 2) ? 4160000 : 7360000;
        const float* F = (l == 0) ? f0 : (l == 1) ? f1 : (l == 2) ? f2 : f3;
        const float* W = (l == 0) ? W0 : (l == 1) ? W1 : (l == 2) ? W2 : W3;
        const int CRB[4] = {0, 1, 5, 14};   // crowBase per c-block

        float4 acc[4];
#pragma unroll
        for (int la = 0; la < 4; ++la)
            acc[la] = *(const float4*)(F + (size_t)(a0 + la) * MK + m * K + q);

        for (int j = 0; j < 4 - l; ++j) {
            const int c = l + j;
            const int crow = CRB[c] + l * l + m;   // row within atom's 30 coupled rows
#pragma unroll
            for (int kk = 0; kk < 32; ++kk) {
                const float4 w = *(const float4*)(W + (size_t)(32 * j + kk) * K + q);
#pragma unroll
                for (int la = 0; la < 4; ++la) {
                    const float cv = clds[(la * 30 + crow) * 33 + kk];
                    acc[la].x += cv * w.x; acc[la].y += cv * w.y;
                    acc[la].z += cv * w.z; acc[la].w += cv * w.w;
                }
            }
        }
#pragma unroll
        for (int la = 0; la < 4; ++la)
            *(float4*)(out + Ol + (size_t)(a0 + la) * MK + m * K + q) = acc[la];
    }
}

extern "C" void kernel_launch(void* const* d_in, const int* in_sizes, int n_in,
                              void* d_out, int out_size, void* d_ws, size_t ws_size,
                              hipStream_t stream)
{
    int ir, ish[4], ift[4], iwr[4], iu[4], iwl[4], ic, in_;
    if (in_sizes[2] == 300000) {
        ir = 0;
        for (int l = 0; l < 4; ++l) { ish[l] = 1 + l; ift[l] = 5 + l; iwr[l] = 9 + l; iu[l] = 13 + l; iwl[l] = 17 + l; }
        ic = 21; in_ = 22;
    } else {
        ir = 0;
        for (int l = 0; l < 4; ++l) { ish[l] = 1 + 5 * l; ift[l] = 2 + 5 * l; iwr[l] = 3 + 5 * l; iu[l] = 4 + 5 * l; iwl[l] = 5 + 5 * l; }
        ic = 21; in_ = 22;
    }
    const float* r   = (const float*)d_in[ir];
    const float* sh0 = (const float*)d_in[ish[0]];
    const float* sh1 = (const float*)d_in[ish[1]];
    const float* sh2 = (const float*)d_in[ish[2]];
    const float* sh3 = (const float*)d_in[ish[3]];
    const float* f0  = (const float*)d_in[ift[0]];
    const float* f1  = (const float*)d_in[ift[1]];
    const float* f2  = (const float*)d_in[ift[2]];
    const float* f3  = (const float*)d_in[ift[3]];
    const float* Wr0 = (const float*)d_in[iwr[0]];
    const float* Wr1 = (const float*)d_in[iwr[1]];
    const float* Wr2 = (const float*)d_in[iwr[2]];
    const float* Wr3 = (const float*)d_in[iwr[3]];
    const float* U0  = (const float*)d_in[iu[0]];
    const float* U1  = (const float*)d_in[iu[1]];
    const float* U2  = (const float*)d_in[iu[2]];
    const float* U3  = (const float*)d_in[iu[3]];
    const float* Wl0 = (const float*)d_in[iwl[0]];
    const float* Wl1 = (const float*)d_in[iwl[1]];
    const float* Wl2 = (const float*)d_in[iwl[2]];
    const float* Wl3 = (const float*)d_in[iwl[3]];
    const int* centers   = (const int*)d_in[ic];
    const int* neighbors = (const int*)d_in[in_];

    uint4* uncf16 = (uint4*)d_ws;                            // NA*160 uint4 = 25.6 MB
    float* pooled = (float*)(uncf16 + (size_t)NA * 160);     // NA*1280 f32 = 51.2 MB
    float* rbbuf  = pooled + (size_t)NA * 1280;              // NE*8 f32    = 3.2 MB
    uint2* csh    = (uint2*)(rbbuf + (size_t)NE * 8);        // NE*40 uint2 = 32 MB
    int*   nbrs    = (int*)(csh + (size_t)NE * 40);          // NE
    int*   counts  = nbrs + NE;                              // NA
    int*   offsets = counts + NA;                            // NA+1
    int*   cursor  = offsets + NA + 1;                       // NA
    float* outp   = (float*)d_out;

    hipMemsetAsync(counts, 0, NA * sizeof(int), stream);
    kCount<<<(NE + 255) / 256, 256, 0, stream>>>(centers, counts);
    kScan<<<1, 1024, 0, stream>>>(counts, offsets, cursor);
    kPrep<<<1250 + (NE + 255) / 256, 256, 0, stream>>>(
        f0, f1, f2, f3, r, sh0, sh1, sh2, sh3, U0, U1, U2, U3,
        centers, neighbors, cursor, uncf16, rbbuf, csh, nbrs);
    kB2<<<NA / 4, 256, 0, stream>>>(Wr0, Wr1, Wr2, Wr3, offsets, nbrs,
                                    rbbuf, csh, uncf16, pooled);
    kC_out<<<NA / 4, 256, 0, stream>>>(pooled, f0, f1, f2, f3, U0, U1, U2, U3,
                                       Wl0, Wl1, Wl2, Wl3, outp);
}